// Round 1
// baseline (216.576 us; speedup 1.0000x reference)
//
#include <hip/hip_runtime.h>
#include <math.h>

// Problem constants (fixed shapes from the reference):
//   b_edges: (64,1,512,512) f32, sobel: (64,2,512,512) f32
//   BASE=256, PY_SIZES=[256,64]
#define NB0 16384      // level-0 pixels 64*256*256 / 256 threads
#define NB1 1024       // level-1 pixels 64*64*64   / 256 threads
#define OFFSET1 4194304  // lin_id offset of level 1 (=64*256*256)

// align_corners coefficient for 512->256: pos = i*511/255 (f32, IEEE div,
// matches jnp.arange(256,f32)*(511)/(255))
__device__ __forceinline__ void ac_coef(int i, int& lo, int& hi, float& w) {
    float p = (float)(i * 511) / 255.0f;
    int l = (int)p;                      // p >= 0 -> trunc == floor
    lo = l;
    hi = (l + 1 < 511) ? (l + 1) : 511;
    w = p - (float)l;
}

// Two-pass bilinear identical in structure to the reference (H interp then W)
__device__ __forceinline__ float bilin(const float* __restrict__ img,
                                       int ly, int hy, float wy,
                                       int lx, int hx, float wx) {
    float a = img[ly * 512 + lx];
    float b = img[ly * 512 + hx];
    float c = img[hy * 512 + lx];
    float d = img[hy * 512 + hx];
    float rl = a * (1.0f - wy) + c * wy;
    float rh = b * (1.0f - wy) + d * wy;
    return rl * (1.0f - wx) + rh * wx;
}

// predicate of level-0 pixel (b,y,x): bilinear(b_edges) != 0
__device__ __forceinline__ bool pred0(const float* __restrict__ E, int b, int y, int x) {
    int ly, hy, lx, hx; float wy, wx;
    ac_coef(y, ly, hy, wy);
    ac_coef(x, lx, hx, wx);
    const float* img = E + (size_t)b * 262144;
    return bilin(img, ly, hy, wy, lx, hx, wx) != 0.0f;
}

// predicate of level-1 pixel (b,Y,X): any of its 4x4 level-0 children nonzero
__device__ __forceinline__ bool pred1(const float* __restrict__ E, int b, int Y, int X) {
    const float* img = E + (size_t)b * 262144;
    bool p = false;
    #pragma unroll
    for (int dy = 0; dy < 4; ++dy) {
        int ly, hy; float wy;
        ac_coef(4 * Y + dy, ly, hy, wy);
        #pragma unroll
        for (int dx = 0; dx < 4; ++dx) {
            int lx, hx; float wx;
            ac_coef(4 * X + dx, lx, hx, wx);
            p |= (bilin(img, ly, hy, wy, lx, hx, wx) != 0.0f);
        }
    }
    return p;
}

__global__ __launch_bounds__(256) void count0_kernel(const float* __restrict__ E,
                                                     int* __restrict__ counts) {
    int tid = threadIdx.x;
    int p = blockIdx.x * 256 + tid;
    int b = p >> 16, y = (p >> 8) & 255, x = p & 255;
    bool pr = pred0(E, b, y, x);
    __shared__ int lds[4];
    unsigned long long m = __ballot(pr);
    if ((tid & 63) == 0) lds[tid >> 6] = __popcll(m);
    __syncthreads();
    if (tid == 0) counts[blockIdx.x] = lds[0] + lds[1] + lds[2] + lds[3];
}

__global__ __launch_bounds__(256) void count1_kernel(const float* __restrict__ E,
                                                     int* __restrict__ counts) {
    int tid = threadIdx.x;
    int q = blockIdx.x * 256 + tid;
    int b = q >> 12, Y = (q >> 6) & 63, X = q & 63;
    bool pr = pred1(E, b, Y, X);
    __shared__ int lds[4];
    unsigned long long m = __ballot(pr);
    if ((tid & 63) == 0) lds[tid >> 6] = __popcll(m);
    __syncthreads();
    if (tid == 0) counts[blockIdx.x] = lds[0] + lds[1] + lds[2] + lds[3];
}

// single-block exclusive scan of both count arrays (sizes are multiples of 256)
__global__ __launch_bounds__(256) void scan_kernel(const int* __restrict__ counts0,
                                                   int* __restrict__ offs0,
                                                   const int* __restrict__ counts1,
                                                   int* __restrict__ offs1,
                                                   int* __restrict__ totals) {
    __shared__ int lds[4];
    int tid = threadIdx.x, lane = tid & 63, wave = tid >> 6;
    int carry = 0;
    for (int base = 0; base < NB0; base += 256) {
        int v = counts0[base + tid];
        int inc = v;
        #pragma unroll
        for (int d = 1; d < 64; d <<= 1) {
            int t = __shfl_up(inc, (unsigned)d, 64);
            if (lane >= d) inc += t;
        }
        if (lane == 63) lds[wave] = inc;
        __syncthreads();
        int wbase = 0;
        for (int i = 0; i < wave; ++i) wbase += lds[i];
        offs0[base + tid] = carry + wbase + inc - v;
        carry += lds[0] + lds[1] + lds[2] + lds[3];
        __syncthreads();
    }
    if (tid == 0) totals[0] = carry;
    int carry1 = 0;
    for (int base = 0; base < NB1; base += 256) {
        int v = counts1[base + tid];
        int inc = v;
        #pragma unroll
        for (int d = 1; d < 64; d <<= 1) {
            int t = __shfl_up(inc, (unsigned)d, 64);
            if (lane >= d) inc += t;
        }
        if (lane == 63) lds[wave] = inc;
        __syncthreads();
        int wbase = 0;
        for (int i = 0; i < wave; ++i) wbase += lds[i];
        offs1[base + tid] = carry1 + wbase + inc - v;
        carry1 += lds[0] + lds[1] + lds[2] + lds[3];
        __syncthreads();
    }
    if (tid == 0) totals[1] = carry1;
}

// intra-block deterministic rank via ballot + wave offsets in LDS
__device__ __forceinline__ int block_rank(bool pr, int tid, int* lds) {
    int lane = tid & 63, wave = tid >> 6;
    unsigned long long m = __ballot(pr);
    if (lane == 0) lds[wave] = __popcll(m);
    __syncthreads();
    int wbase = 0;
    for (int i = 0; i < wave; ++i) wbase += lds[i];
    return wbase + __popcll(m & ((1ull << lane) - 1ull));
}

__device__ __forceinline__ void write_row(float* __restrict__ out, int N, int row,
                                          float cy, float cx, float s0, float s1,
                                          float half, float sz, float imgid,
                                          float prow, float mylin) {
    float len = sqrtf(s0 * s0 + s1 * s1);
    float n0 = s0 / len, n1 = s1 / len;
    float rt0 = n1 * half, rt1 = -n0 * half;
    out[2 * row + 0] = cy + rt0;                 // locs_lf
    out[2 * row + 1] = cx + rt1;
    out[2 * N + 2 * row + 0] = cy - rt0;         // locs_rt
    out[2 * N + 2 * row + 1] = cx - rt1;
    out[4 * N + 2 * row + 0] = n0;               // norms
    out[4 * N + 2 * row + 1] = n1;
    out[6 * N + row] = sz;                       // sizes
    out[7 * N + 2 * row + 0] = cy;               // centers
    out[7 * N + 2 * row + 1] = cx;
    out[9 * N + row] = imgid;                    // imgid
    out[10 * N + row] = prow;                    // p_rowids
    out[11 * N + row] = mylin;                   // my_lin
}

// level-1 scatter: rows [N0, N0+N1); also writes rank1[] = global row for parents
__global__ __launch_bounds__(256) void scatter1_kernel(const float* __restrict__ E,
                                                       const float* __restrict__ S,
                                                       const int* __restrict__ offs1,
                                                       const int* __restrict__ totals,
                                                       int* __restrict__ rank1,
                                                       float* __restrict__ out, int N) {
    int tid = threadIdx.x;
    int q = blockIdx.x * 256 + tid;
    int b = q >> 12, Y = (q >> 6) & 63, X = q & 63;
    bool pr = pred1(E, b, Y, X);
    __shared__ int lds[4];
    int r = block_rank(pr, tid, lds);
    if (!pr) return;
    int row = totals[0] + offs1[blockIdx.x] + r;
    rank1[q] = row;
    // s1 = 4x4 area pool of bilinear-resized sobel (2 channels)
    const float* sb0 = S + (size_t)(b * 2 + 0) * 262144;
    const float* sb1 = S + (size_t)(b * 2 + 1) * 262144;
    float a0 = 0.0f, a1 = 0.0f;
    #pragma unroll
    for (int dy = 0; dy < 4; ++dy) {
        int ly, hy; float wy;
        ac_coef(4 * Y + dy, ly, hy, wy);
        #pragma unroll
        for (int dx = 0; dx < 4; ++dx) {
            int lx, hx; float wx;
            ac_coef(4 * X + dx, lx, hx, wx);
            a0 += bilin(sb0, ly, hy, wy, lx, hx, wx);
            a1 += bilin(sb1, ly, hy, wy, lx, hx, wx);
        }
    }
    a0 *= (1.0f / 16.0f);
    a1 *= (1.0f / 16.0f);
    float cy = ((float)Y + 0.5f) * 4.0f;
    float cx = ((float)X + 0.5f) * 4.0f;
    write_row(out, N, row, cy, cx, a0, a1, 2.0f, 4.0f, (float)b,
              (float)row, (float)(OFFSET1 + q));
}

// level-0 scatter: rows [0, N0); parent row via rank1[]
__global__ __launch_bounds__(256) void scatter0_kernel(const float* __restrict__ E,
                                                       const float* __restrict__ S,
                                                       const int* __restrict__ offs0,
                                                       const int* __restrict__ rank1,
                                                       float* __restrict__ out, int N) {
    int tid = threadIdx.x;
    int p = blockIdx.x * 256 + tid;
    int b = p >> 16, y = (p >> 8) & 255, x = p & 255;
    bool pr = pred0(E, b, y, x);
    __shared__ int lds[4];
    int r = block_rank(pr, tid, lds);
    if (!pr) return;
    int row = offs0[blockIdx.x] + r;
    int ly, hy, lx, hx; float wy, wx;
    ac_coef(y, ly, hy, wy);
    ac_coef(x, lx, hx, wx);
    const float* sb0 = S + (size_t)(b * 2 + 0) * 262144;
    const float* sb1 = S + (size_t)(b * 2 + 1) * 262144;
    float a0 = bilin(sb0, ly, hy, wy, lx, hx, wx);
    float a1 = bilin(sb1, ly, hy, wy, lx, hx, wx);
    float cy = (float)y + 0.5f;
    float cx = (float)x + 0.5f;
    int parent = (b << 12) + ((y >> 2) << 6) + (x >> 2);
    int prow = rank1[parent];
    write_row(out, N, row, cy, cx, a0, a1, 0.5f, 1.0f, (float)b,
              (float)prow, (float)p);
}

extern "C" void kernel_launch(void* const* d_in, const int* in_sizes, int n_in,
                              void* d_out, int out_size, void* d_ws, size_t ws_size,
                              hipStream_t stream) {
    const float* E = (const float*)d_in[0];   // b_edges (64,1,512,512)
    const float* S = (const float*)d_in[1];   // sobel   (64,2,512,512)
    float* out = (float*)d_out;
    int N = out_size / 12;                    // rows: 8 outputs = 12 floats/row

    int* ws = (int*)d_ws;                     // ~1.19 MB of scratch used
    int* counts0 = ws;                        // [NB0]
    int* offs0   = counts0 + NB0;             // [NB0]
    int* counts1 = offs0 + NB0;               // [NB1]
    int* offs1   = counts1 + NB1;             // [NB1]
    int* totals  = offs1 + NB1;               // [2] {N0, N1}
    int* rank1   = totals + 2;                // [64*64*64] global row of L1 edges

    count0_kernel<<<NB0, 256, 0, stream>>>(E, counts0);
    count1_kernel<<<NB1, 256, 0, stream>>>(E, counts1);
    scan_kernel<<<1, 256, 0, stream>>>(counts0, offs0, counts1, offs1, totals);
    scatter1_kernel<<<NB1, 256, 0, stream>>>(E, S, offs1, totals, rank1, out, N);
    scatter0_kernel<<<NB0, 256, 0, stream>>>(E, S, offs0, rank1, out, N);
}

// Round 2
// 93.881 us; speedup vs baseline: 2.3069x; 2.3069x over previous
//
#include <hip/hip_runtime.h>
#include <math.h>

// Fixed shapes: b_edges (64,1,512,512) f32, sobel (64,2,512,512) f32
// BASE=256, PY_SIZES=[256,64]
#define OFFSET1 4194304   // lin_id offset of level 1 (=64*256*256)

// align_corners coefficient for 512->256: pos = (i*511)/255 in f32 (exact match
// to jnp.arange(256,f32)*511/255: i*511 < 2^24 so the product is exact, then
// one IEEE f32 division).
__device__ __forceinline__ void ac_coef(int i, int& lo, int& hi, float& w) {
    float p = (float)(i * 511) / 255.0f;
    int l = (int)p;                       // p >= 0 -> trunc == floor
    lo = l;
    hi = (l + 1 < 511) ? (l + 1) : 511;
    w = p - (float)l;
}

__device__ __forceinline__ float bilin(const float* __restrict__ img,
                                       int ly, int hy, float wy,
                                       int lx, int hx, float wx) {
    float a = img[ly * 512 + lx];
    float b = img[ly * 512 + hx];
    float c = img[hy * 512 + lx];
    float d = img[hy * 512 + hx];
    float rl = a * (1.0f - wy) + c * wy;   // H interp first (matches reference)
    float rh = b * (1.0f - wy) + d * wy;
    return rl * (1.0f - wx) + rh * wx;     // then W interp
}

// ---------------------------------------------------------------------------
// prep: one pass over all level-0 pixels. Block = (img b, row-group R) covering
// output rows 4R..4R+3 (4 rows x 256 cols = 1024 threads). Produces:
//   - mask0: level-0 predicate bits (1 bit / pixel, ballot words)
//   - counts0[block]: # active level-0 pixels in this block
//   - s0 (optional): resized sobel, interleaved (ch0,ch1) per pixel
//   - s1: 4x4 area-pooled sobel for the block's level-1 row (64 X values)
//   - mask1[b*64+R], counts1[b*64+R]: level-1 predicate + count
// ---------------------------------------------------------------------------
__global__ __launch_bounds__(1024) void prep_kernel(const float* __restrict__ E,
                                                    const float* __restrict__ S,
                                                    float* __restrict__ s0,
                                                    float* __restrict__ s1,
                                                    unsigned long long* __restrict__ mask0,
                                                    unsigned long long* __restrict__ mask1,
                                                    int* __restrict__ counts0,
                                                    int* __restrict__ counts1,
                                                    int use_s0) {
    int tid = threadIdx.x;
    int blk = blockIdx.x;                 // b*64 + R
    int b = blk >> 6, R = blk & 63;
    int r = tid >> 8, x = tid & 255;
    int y = 4 * R + r;
    int lane = tid & 63, wave = tid >> 6;

    int ly, hy, lx, hx; float wy, wx;
    ac_coef(y, ly, hy, wy);
    ac_coef(x, lx, hx, wx);

    const float* Eb = E + (size_t)b * 262144;
    bool pr = (bilin(Eb, ly, hy, wy, lx, hx, wx) != 0.0f);

    const float* Sb0 = S + (size_t)(b * 2 + 0) * 262144;
    const float* Sb1 = S + (size_t)(b * 2 + 1) * 262144;
    float v0 = bilin(Sb0, ly, hy, wy, lx, hx, wx);
    float v1 = bilin(Sb1, ly, hy, wy, lx, hx, wx);

    if (use_s0) {
        ((float2*)s0)[(size_t)(b * 256 + y) * 256 + x] = make_float2(v0, v1);
    }

    __shared__ int wc[16];
    unsigned long long m = __ballot(pr);
    if (lane == 0) {
        // word index = linear_pixel_index / 64 (x is 64-aligned at lane 0)
        mask0[(size_t)b * 1024 + y * 4 + (x >> 6)] = m;
        wc[wave] = __popcll(m);
    }

    // horizontal sum over groups of 4 adjacent x (same wave)
    float h0 = v0 + __shfl_xor(v0, 1, 64); h0 += __shfl_xor(h0, 2, 64);
    float h1 = v1 + __shfl_xor(v1, 1, 64); h1 += __shfl_xor(h1, 2, 64);
    int   hp = pr ? 1 : 0;
    hp += __shfl_xor(hp, 1, 64); hp += __shfl_xor(hp, 2, 64);

    __shared__ float sA[4][64];
    __shared__ float sB[4][64];
    __shared__ int   sP[4][64];
    if ((x & 3) == 0) {
        int X = x >> 2;                    // 0..63
        sA[r][X] = h0; sB[r][X] = h1; sP[r][X] = hp;
    }
    __syncthreads();

    if (tid < 64) {                        // wave 0: one lane per level-1 X
        int X = tid;
        float a  = sA[0][X] + sA[1][X] + sA[2][X] + sA[3][X];
        float c2 = sB[0][X] + sB[1][X] + sB[2][X] + sB[3][X];
        int   pp = sP[0][X] + sP[1][X] + sP[2][X] + sP[3][X];
        bool p1 = (pp > 0);
        unsigned long long m1 = __ballot(p1);
        ((float2*)s1)[(size_t)blk * 64 + X] = make_float2(a * (1.0f / 16.0f),
                                                          c2 * (1.0f / 16.0f));
        if (tid == 0) { mask1[blk] = m1; counts1[blk] = __popcll(m1); }
    }
    if (tid == 0) {
        int t = 0;
        #pragma unroll
        for (int i = 0; i < 16; ++i) t += wc[i];
        counts0[blk] = t;
    }
}

// single-block exclusive scan of counts0[4096] and counts1[4096]
__global__ __launch_bounds__(1024) void scan_kernel(const int* __restrict__ counts0,
                                                    int* __restrict__ offs0,
                                                    const int* __restrict__ counts1,
                                                    int* __restrict__ offs1,
                                                    int* __restrict__ totals) {
    __shared__ int wsum[16];
    int tid = threadIdx.x, lane = tid & 63, wave = tid >> 6;

    int carry = 0;
    for (int base = 0; base < 4096; base += 1024) {
        int v = counts0[base + tid];
        int inc = v;
        #pragma unroll
        for (int d = 1; d < 64; d <<= 1) {
            int t = __shfl_up(inc, (unsigned)d, 64);
            if (lane >= d) inc += t;
        }
        if (lane == 63) wsum[wave] = inc;
        __syncthreads();
        int wbase = 0;
        for (int i = 0; i < wave; ++i) wbase += wsum[i];
        int tot = 0;
        #pragma unroll
        for (int i = 0; i < 16; ++i) tot += wsum[i];
        offs0[base + tid] = carry + wbase + inc - v;
        carry += tot;
        __syncthreads();
    }
    if (tid == 0) totals[0] = carry;

    int carry1 = 0;
    for (int base = 0; base < 4096; base += 1024) {
        int v = counts1[base + tid];
        int inc = v;
        #pragma unroll
        for (int d = 1; d < 64; d <<= 1) {
            int t = __shfl_up(inc, (unsigned)d, 64);
            if (lane >= d) inc += t;
        }
        if (lane == 63) wsum[wave] = inc;
        __syncthreads();
        int wbase = 0;
        for (int i = 0; i < wave; ++i) wbase += wsum[i];
        int tot = 0;
        #pragma unroll
        for (int i = 0; i < 16; ++i) tot += wsum[i];
        offs1[base + tid] = carry1 + wbase + inc - v;
        carry1 += tot;
        __syncthreads();
    }
    if (tid == 0) totals[1] = carry1;
}

__device__ __forceinline__ void write_row(float* __restrict__ out, int N, int row,
                                          float cy, float cx, float s0v, float s1v,
                                          float half, float sz, float imgid,
                                          float prow, float mylin) {
    float len = sqrtf(s0v * s0v + s1v * s1v);
    float n0 = s0v / len, n1 = s1v / len;
    float rt0 = n1 * half, rt1 = -n0 * half;
    out[2 * row + 0] = cy + rt0;                 // locs_lf
    out[2 * row + 1] = cx + rt1;
    out[2 * N + 2 * row + 0] = cy - rt0;         // locs_rt
    out[2 * N + 2 * row + 1] = cx - rt1;
    out[4 * N + 2 * row + 0] = n0;               // norms
    out[4 * N + 2 * row + 1] = n1;
    out[6 * N + row] = sz;                       // sizes
    out[7 * N + 2 * row + 0] = cy;               // centers
    out[7 * N + 2 * row + 1] = cx;
    out[9 * N + row] = imgid;                    // imgid
    out[10 * N + row] = prow;                    // p_rowids
    out[11 * N + row] = mylin;                   // my_lin
}

// level-1 scatter: one wave per (b,Y) group of 64 X. Rows [N0, N0+N1).
__global__ __launch_bounds__(1024) void scatter1_kernel(const float* __restrict__ s1,
                                                        const unsigned long long* __restrict__ mask1,
                                                        const int* __restrict__ offs1,
                                                        const int* __restrict__ totals,
                                                        int* __restrict__ rank1,
                                                        float* __restrict__ out, int N) {
    int tid = threadIdx.x, lane = tid & 63, wave = tid >> 6;
    int g = blockIdx.x * 16 + wave;              // 0..4095 = b*64 + Y
    unsigned long long m = mask1[g];
    bool pr = (m >> lane) & 1ull;
    if (!pr) return;
    int row = totals[0] + offs1[g] + __popcll(m & ((1ull << lane) - 1ull));
    int q = g * 64 + lane;                       // linear L1 index
    rank1[q] = row;
    float2 sv = ((const float2*)s1)[q];
    int b = g >> 6, Y = g & 63, X = lane;
    float cy = ((float)Y + 0.5f) * 4.0f;
    float cx = ((float)X + 0.5f) * 4.0f;
    write_row(out, N, row, cy, cx, sv.x, sv.y, 2.0f, 4.0f, (float)b,
              (float)row, (float)(OFFSET1 + q));
}

// level-0 scatter: rows [0, N0). Block layout mirrors prep (b, R, 4 rows x 256).
__global__ __launch_bounds__(1024) void scatter0_kernel(const float* __restrict__ S,
                                                        const float* __restrict__ s0,
                                                        const unsigned long long* __restrict__ mask0,
                                                        const int* __restrict__ offs0,
                                                        const int* __restrict__ rank1,
                                                        float* __restrict__ out, int N,
                                                        int use_s0) {
    int tid = threadIdx.x, lane = tid & 63, wave = tid >> 6;
    int blk = blockIdx.x;                        // b*64 + R
    int b = blk >> 6, R = blk & 63;
    int r = tid >> 8, x = tid & 255;
    int y = 4 * R + r;
    int p = (b << 16) + (y << 8) + x;
    unsigned long long m = mask0[p >> 6];
    __shared__ int wc[16];
    if (lane == 0) wc[wave] = __popcll(m);
    __syncthreads();
    bool pr = (m >> lane) & 1ull;
    if (!pr) return;
    int wbase = 0;
    for (int i = 0; i < wave; ++i) wbase += wc[i];
    int row = offs0[blk] + wbase + __popcll(m & ((1ull << lane) - 1ull));

    float v0, v1;
    if (use_s0) {
        float2 sv = ((const float2*)s0)[(size_t)(b * 256 + y) * 256 + x];
        v0 = sv.x; v1 = sv.y;
    } else {
        int ly, hy, lx, hx; float wy, wx;
        ac_coef(y, ly, hy, wy);
        ac_coef(x, lx, hx, wx);
        v0 = bilin(S + (size_t)(b * 2 + 0) * 262144, ly, hy, wy, lx, hx, wx);
        v1 = bilin(S + (size_t)(b * 2 + 1) * 262144, ly, hy, wy, lx, hx, wx);
    }
    float cy = (float)y + 0.5f;
    float cx = (float)x + 0.5f;
    int parent = (b << 12) + ((y >> 2) << 6) + (x >> 2);
    write_row(out, N, row, cy, cx, v0, v1, 0.5f, 1.0f, (float)b,
              (float)rank1[parent], (float)p);
}

extern "C" void kernel_launch(void* const* d_in, const int* in_sizes, int n_in,
                              void* d_out, int out_size, void* d_ws, size_t ws_size,
                              hipStream_t stream) {
    const float* E = (const float*)d_in[0];   // b_edges (64,1,512,512)
    const float* S = (const float*)d_in[1];   // sobel   (64,2,512,512)
    float* out = (float*)d_out;
    int N = out_size / 12;                    // 8 outputs = 12 floats/row

    // workspace layout (bytes)
    char* ws = (char*)d_ws;
    int*  rank1   = (int*)ws;                               // 262144 ints = 1 MB
    int*  counts0 = (int*)(ws + 1048576);                   // 4096
    int*  offs0   = counts0 + 4096;
    int*  counts1 = offs0 + 4096;
    int*  offs1   = counts1 + 4096;
    int*  totals  = offs1 + 4096;                           // 2 (+pad)
    unsigned long long* mask0 = (unsigned long long*)(ws + 1048576 + 65536 + 64); // 512 KB
    unsigned long long* mask1 = mask0 + 65536;              // 32 KB
    float* s1 = (float*)(mask1 + 4096);                     // 524288 floats = 2 MB
    float* s0 = s1 + 524288;                                // 8388608 floats = 32 MB
    size_t need_with_s0 = (size_t)(s0 + 16777216 - (float*)ws) * sizeof(float) / sizeof(float);
    size_t base_bytes = (size_t)((char*)(s1 + 524288) - ws);
    int use_s0 = (ws_size >= base_bytes + 8388608ull * 8ull) ? 1 : 0;
    (void)need_with_s0;

    prep_kernel<<<4096, 1024, 0, stream>>>(E, S, use_s0 ? (float*)s0 : nullptr, s1,
                                           mask0, mask1, counts0, counts1, use_s0);
    scan_kernel<<<1, 1024, 0, stream>>>(counts0, offs0, counts1, offs1, totals);
    scatter1_kernel<<<256, 1024, 0, stream>>>(s1, mask1, offs1, totals, rank1, out, N);
    scatter0_kernel<<<4096, 1024, 0, stream>>>(S, (const float*)s0, mask0, offs0,
                                               rank1, out, N, use_s0);
}

// Round 3
// 82.993 us; speedup vs baseline: 2.6096x; 1.1312x over previous
//
#include <hip/hip_runtime.h>
#include <math.h>

// Fixed shapes: b_edges (64,1,512,512) f32, sobel (64,2,512,512) f32
// BASE=256, PY_SIZES=[256,64]
#define OFFSET1 4194304   // lin_id offset of level 1 (=64*256*256)

// ---- generic align-corners helpers (used only by the no-s0 fallback) ------
__device__ __forceinline__ void ac_coef(int i, int& lo, int& hi, float& w) {
    float p = (float)(i * 511) / 255.0f;
    int l = (int)p;
    lo = l;
    hi = (l + 1 < 511) ? (l + 1) : 511;
    w = p - (float)l;
}
__device__ __forceinline__ float bilin(const float* __restrict__ img,
                                       int ly, int hy, float wy,
                                       int lx, int hx, float wx) {
    float a = img[ly * 512 + lx];
    float b = img[ly * 512 + hx];
    float c = img[hy * 512 + lx];
    float d = img[hy * 512 + hx];
    float rl = a * (1.0f - wy) + c * wy;
    float rh = b * (1.0f - wy) + d * wy;
    return rl * (1.0f - wx) + rh * wx;
}

// expand 32 bits to even bit positions of a 64-bit word
__device__ __forceinline__ unsigned long long expand_bits(unsigned long long x) {
    x &= 0xFFFFFFFFull;
    x = (x | (x << 16)) & 0x0000FFFF0000FFFFull;
    x = (x | (x << 8))  & 0x00FF00FF00FF00FFull;
    x = (x | (x << 4))  & 0x0F0F0F0F0F0F0F0Full;
    x = (x | (x << 2))  & 0x3333333333333333ull;
    x = (x | (x << 1))  & 0x5555555555555555ull;
    return x;
}

// ---------------------------------------------------------------------------
// prep: block = (b, R) covering output rows 4R..4R+3, 512 threads, each thread
// computes 2 adjacent output pixels. Key identity for 512->256 align-corners:
// lo(i) = 2i exactly and w(i) = pos(i) - 2i (i=255 gives w=1.0 — value is
// bit-identical to the reference's lo=hi=511, w=0 form). So each thread's two
// pixels need input cols [4xh, 4xh+3] of rows 2y,2y+1 -> float4 loads.
// ---------------------------------------------------------------------------
__global__ __launch_bounds__(512) void prep_kernel(const float* __restrict__ E,
                                                   const float* __restrict__ S,
                                                   float* __restrict__ s0,
                                                   float* __restrict__ s1,
                                                   unsigned long long* __restrict__ mask0,
                                                   unsigned long long* __restrict__ mask1,
                                                   int* __restrict__ counts0,
                                                   int* __restrict__ counts1,
                                                   int use_s0) {
    int tid = threadIdx.x;
    int blk = blockIdx.x;                 // b*64 + R
    int b = blk >> 6, R = blk & 63;
    int r = tid >> 7, xh = tid & 127;     // row-in-block, x-pair index
    int y = 4 * R + r;
    int lane = tid & 63, wave = tid >> 6; // wave = 2r + (xh>>6)
    int half = wave & 1;

    // y weights (uniform lo=2y, works for y=255 too: wy=1.0)
    int ly = 2 * y;
    float wy = (float)(y * 511) / 255.0f - (float)ly;
    // x weights for pixels x0=2xh, x1=2xh+1 (taps at cols 4xh.. / +2..)
    int x0 = 2 * xh;
    float wx0 = (float)(x0 * 511) / 255.0f - (float)(4 * xh);
    float wx1 = (float)((x0 + 1) * 511) / 255.0f - (float)(4 * xh + 2);

    int off = b * 262144 + ly * 512 + 4 * xh;
    float4 eL = *(const float4*)(E + off);
    float4 eH = *(const float4*)(E + off + 512);
    int offS = b * 524288 + ly * 512 + 4 * xh;
    float4 aL = *(const float4*)(S + offS);
    float4 aH = *(const float4*)(S + offS + 512);
    float4 bL = *(const float4*)(S + offS + 262144);
    float4 bH = *(const float4*)(S + offS + 262144 + 512);

    float omwy = 1.0f - wy;
    #define IPX(lo4a, lo4b, hi4a, hi4b, wx) \
        ((lo4a * omwy + hi4a * wy) * (1.0f - wx) + (lo4b * omwy + hi4b * wy) * wx)
    float e0v = IPX(eL.x, eL.y, eH.x, eH.y, wx0);
    float e1v = IPX(eL.z, eL.w, eH.z, eH.w, wx1);
    float v00 = IPX(aL.x, aL.y, aH.x, aH.y, wx0);
    float v01 = IPX(aL.z, aL.w, aH.z, aH.w, wx1);
    float v10 = IPX(bL.x, bL.y, bH.x, bH.y, wx0);
    float v11 = IPX(bL.z, bL.w, bH.z, bH.w, wx1);
    #undef IPX
    bool pr0 = (e0v != 0.0f), pr1 = (e1v != 0.0f);

    if (use_s0) {
        ((float4*)s0)[(b * 256 + y) * 128 + xh] = make_float4(v00, v10, v01, v11);
    }

    __shared__ int wc[8];
    unsigned long long mE = __ballot(pr0);
    unsigned long long mO = __ballot(pr1);
    if (lane == 0) {
        int wbase = b * 1024 + y * 4 + 2 * half;
        mask0[wbase]     = expand_bits(mE) | (expand_bits(mO) << 1);
        mask0[wbase + 1] = expand_bits(mE >> 32) | (expand_bits(mO >> 32) << 1);
        wc[wave] = __popcll(mE) + __popcll(mO);
    }

    // level-1: sum 4x4 (2 in-thread + lane-pair + 4 rows via LDS)
    float t0 = v00 + v01, t1 = v10 + v11;
    int ip = (pr0 || pr1) ? 1 : 0;
    float h0 = t0 + __shfl_xor(t0, 1, 64);
    float h1 = t1 + __shfl_xor(t1, 1, 64);
    ip |= __shfl_xor(ip, 1, 64);

    __shared__ float sA[4][64];
    __shared__ float sB[4][64];
    __shared__ int   sP[4][64];
    if ((xh & 1) == 0) {
        int X = (half << 5) + (lane >> 1);   // = xh>>1, 0..63
        sA[r][X] = h0; sB[r][X] = h1; sP[r][X] = ip;
    }
    __syncthreads();

    if (tid < 64) {
        int X = tid;
        float a  = sA[0][X] + sA[1][X] + sA[2][X] + sA[3][X];
        float c2 = sB[0][X] + sB[1][X] + sB[2][X] + sB[3][X];
        bool p1 = (sP[0][X] | sP[1][X] | sP[2][X] | sP[3][X]) != 0;
        unsigned long long m1 = __ballot(p1);
        ((float2*)s1)[blk * 64 + X] = make_float2(a * (1.0f / 16.0f),
                                                  c2 * (1.0f / 16.0f));
        if (tid == 0) { mask1[blk] = m1; counts1[blk] = __popcll(m1); }
    }
    if (tid == 0) {
        int t = 0;
        #pragma unroll
        for (int i = 0; i < 8; ++i) t += wc[i];
        counts0[blk] = t;
    }
}

// single-block exclusive scan of counts0[4096] and counts1[4096]
__global__ __launch_bounds__(1024) void scan_kernel(const int* __restrict__ counts0,
                                                    int* __restrict__ offs0,
                                                    const int* __restrict__ counts1,
                                                    int* __restrict__ offs1,
                                                    int* __restrict__ totals) {
    __shared__ int wsum[16];
    int tid = threadIdx.x, lane = tid & 63, wave = tid >> 6;

    int carry = 0;
    for (int base = 0; base < 4096; base += 1024) {
        int v = counts0[base + tid];
        int inc = v;
        #pragma unroll
        for (int d = 1; d < 64; d <<= 1) {
            int t = __shfl_up(inc, (unsigned)d, 64);
            if (lane >= d) inc += t;
        }
        if (lane == 63) wsum[wave] = inc;
        __syncthreads();
        int wbase = 0;
        for (int i = 0; i < wave; ++i) wbase += wsum[i];
        int tot = 0;
        #pragma unroll
        for (int i = 0; i < 16; ++i) tot += wsum[i];
        offs0[base + tid] = carry + wbase + inc - v;
        carry += tot;
        __syncthreads();
    }
    if (tid == 0) totals[0] = carry;

    int carry1 = 0;
    for (int base = 0; base < 4096; base += 1024) {
        int v = counts1[base + tid];
        int inc = v;
        #pragma unroll
        for (int d = 1; d < 64; d <<= 1) {
            int t = __shfl_up(inc, (unsigned)d, 64);
            if (lane >= d) inc += t;
        }
        if (lane == 63) wsum[wave] = inc;
        __syncthreads();
        int wbase = 0;
        for (int i = 0; i < wave; ++i) wbase += wsum[i];
        int tot = 0;
        #pragma unroll
        for (int i = 0; i < 16; ++i) tot += wsum[i];
        offs1[base + tid] = carry1 + wbase + inc - v;
        carry1 += tot;
        __syncthreads();
    }
    if (tid == 0) totals[1] = carry1;
}

__device__ __forceinline__ void write_row(float* __restrict__ out, int N, int row,
                                          float cy, float cx, float s0v, float s1v,
                                          float half, float sz, float imgid,
                                          float prow, float mylin) {
    float len = sqrtf(s0v * s0v + s1v * s1v);
    float n0 = s0v / len, n1 = s1v / len;
    float rt0 = n1 * half, rt1 = -n0 * half;
    ((float2*)out)[row]           = make_float2(cy + rt0, cx + rt1);  // locs_lf
    ((float2*)(out + 2 * N))[row] = make_float2(cy - rt0, cx - rt1);  // locs_rt
    ((float2*)(out + 4 * N))[row] = make_float2(n0, n1);              // norms
    out[6 * N + row] = sz;                                            // sizes
    ((float2*)(out + 7 * N))[row] = make_float2(cy, cx);              // centers
    out[9 * N + row] = imgid;                                         // imgid
    out[10 * N + row] = prow;                                         // p_rowids
    out[11 * N + row] = mylin;                                        // my_lin
}

// level-1 scatter: one wave per (b,Y). Rows [N0, N0+N1).
__global__ __launch_bounds__(1024) void scatter1_kernel(const float* __restrict__ s1,
                                                        const unsigned long long* __restrict__ mask1,
                                                        const int* __restrict__ offs1,
                                                        const int* __restrict__ totals,
                                                        int* __restrict__ rank1,
                                                        float* __restrict__ out, int N) {
    int tid = threadIdx.x, lane = tid & 63, wave = tid >> 6;
    int g = blockIdx.x * 16 + wave;              // 0..4095 = b*64 + Y
    unsigned long long m = mask1[g];
    bool pr = (m >> lane) & 1ull;
    if (!pr) return;
    int row = totals[0] + offs1[g] + __popcll(m & ((1ull << lane) - 1ull));
    int q = g * 64 + lane;
    rank1[q] = row;
    float2 sv = ((const float2*)s1)[q];
    int b = g >> 6, Y = g & 63, X = lane;
    float cy = ((float)Y + 0.5f) * 4.0f;
    float cx = ((float)X + 0.5f) * 4.0f;
    write_row(out, N, row, cy, cx, sv.x, sv.y, 2.0f, 4.0f, (float)b,
              (float)row, (float)(OFFSET1 + q));
}

// level-0 scatter: rows [0, N0). Block = (b, R), 4 rows x 256 cols.
__global__ __launch_bounds__(1024) void scatter0_kernel(const float* __restrict__ S,
                                                        const float* __restrict__ s0,
                                                        const unsigned long long* __restrict__ mask0,
                                                        const int* __restrict__ offs0,
                                                        const int* __restrict__ rank1,
                                                        float* __restrict__ out, int N,
                                                        int use_s0) {
    int tid = threadIdx.x, lane = tid & 63, wave = tid >> 6;
    int blk = blockIdx.x;                        // b*64 + R
    int b = blk >> 6, R = blk & 63;
    int r = tid >> 8, x = tid & 255;
    int y = 4 * R + r;
    int p = (b << 16) + (y << 8) + x;
    unsigned long long m = mask0[p >> 6];
    __shared__ int wc[16];
    if (lane == 0) wc[wave] = __popcll(m);
    __syncthreads();
    bool pr = (m >> lane) & 1ull;
    if (!pr) return;
    int wbase = 0;
    for (int i = 0; i < wave; ++i) wbase += wc[i];
    int row = offs0[blk] + wbase + __popcll(m & ((1ull << lane) - 1ull));

    float v0, v1;
    if (use_s0) {
        float2 sv = ((const float2*)s0)[(b * 256 + y) * 256 + x];
        v0 = sv.x; v1 = sv.y;
    } else {
        int ly, hy, lx, hx; float wy, wx;
        ac_coef(y, ly, hy, wy);
        ac_coef(x, lx, hx, wx);
        v0 = bilin(S + (size_t)(b * 2 + 0) * 262144, ly, hy, wy, lx, hx, wx);
        v1 = bilin(S + (size_t)(b * 2 + 1) * 262144, ly, hy, wy, lx, hx, wx);
    }
    float cy = (float)y + 0.5f;
    float cx = (float)x + 0.5f;
    int parent = (b << 12) + ((y >> 2) << 6) + (x >> 2);
    write_row(out, N, row, cy, cx, v0, v1, 0.5f, 1.0f, (float)b,
              (float)rank1[parent], (float)p);
}

extern "C" void kernel_launch(void* const* d_in, const int* in_sizes, int n_in,
                              void* d_out, int out_size, void* d_ws, size_t ws_size,
                              hipStream_t stream) {
    const float* E = (const float*)d_in[0];   // b_edges (64,1,512,512)
    const float* S = (const float*)d_in[1];   // sobel   (64,2,512,512)
    float* out = (float*)d_out;
    int N = out_size / 12;                    // 8 outputs = 12 floats/row

    // workspace layout (bytes)
    char* ws = (char*)d_ws;
    int*  rank1   = (int*)ws;                               // 262144 ints = 1 MB
    int*  counts0 = (int*)(ws + 1048576);                   // 4096
    int*  offs0   = counts0 + 4096;
    int*  counts1 = offs0 + 4096;
    int*  offs1   = counts1 + 4096;
    int*  totals  = offs1 + 4096;                           // 2 (+pad)
    unsigned long long* mask0 = (unsigned long long*)(ws + 1048576 + 65536 + 64); // 512 KB
    unsigned long long* mask1 = mask0 + 65536;              // 32 KB
    float* s1 = (float*)(mask1 + 4096);                     // 524288 floats = 2 MB
    float* s0 = s1 + 524288;                                // 8388608 float2 = 32 MB
    size_t base_bytes = (size_t)((char*)(s1 + 524288) - ws);
    int use_s0 = (ws_size >= base_bytes + 8388608ull * 8ull) ? 1 : 0;

    prep_kernel<<<4096, 512, 0, stream>>>(E, S, (float*)s0, s1,
                                          mask0, mask1, counts0, counts1, use_s0);
    scan_kernel<<<1, 1024, 0, stream>>>(counts0, offs0, counts1, offs1, totals);
    scatter1_kernel<<<256, 1024, 0, stream>>>(s1, mask1, offs1, totals, rank1, out, N);
    scatter0_kernel<<<4096, 1024, 0, stream>>>(S, (const float*)s0, mask0, offs0,
                                               rank1, out, N, use_s0);
}